// Round 1
// baseline (5729.537 us; speedup 1.0000x reference)
//
#include <hip/hip_runtime.h>
#include <hip/hip_cooperative_groups.h>

namespace cg = cooperative_groups;

// Sizes (fixed by the problem)
//  states [64,32,50,16] -> 2048 seqs x 50 steps x 16
//  LSTM H=256 (gate cols 1024), GAT 256ch, 4 heads x 64
#define TSTEPS 50

__device__ __forceinline__ float sigm(float x) { return 1.0f / (1.0f + expf(-x)); }
__device__ __forceinline__ float gelu_t(float x) {
  float x3 = x * x * x;
  return 0.5f * x * (1.0f + tanhf(0.7978845608028654f * (x + 0.044715f * x3)));
}

// ---- LSTM persistent kernel helpers -------------------------------------
// A-chunk: 16 k-rows x 256 m, stored transposed in LDS As[k][m], row stride 260.
// Coalesced global load: 4 consecutive lanes read 4 consecutive float4 of one row.
__device__ __forceinline__ void load_chunk(float4 r[4], const float* __restrict__ src,
                                           int mbase, int stride, int koff, int tid) {
  const int row = tid >> 2;          // 0..63
  const int c4  = (tid & 3) << 2;    // 0,4,8,12
  const float* p = src + (mbase + row) * stride + koff + c4;
  r[0] = *(const float4*)(p);
  r[1] = *(const float4*)(p + 64 * stride);
  r[2] = *(const float4*)(p + 128 * stride);
  r[3] = *(const float4*)(p + 192 * stride);
}

__device__ __forceinline__ void store_chunk(const float4 r[4], float* __restrict__ A, int tid) {
  const int row = tid >> 2;
  const int k0  = (tid & 3) << 2;
  #pragma unroll
  for (int q = 0; q < 4; ++q) {
    const int m = row + (q << 6);
    A[(k0 + 0) * 260 + m] = r[q].x;   // banks: 16(t&3)+4i+row -> 2-way max (free)
    A[(k0 + 1) * 260 + m] = r[q].y;
    A[(k0 + 2) * 260 + m] = r[q].z;
    A[(k0 + 3) * 260 + m] = r[q].w;
  }
}

// z[mi][g] += A[m0+mi][k] * W[k][g], 16 k-rows. W LDS layout: [k][j*4+g] (32 floats/row).
__device__ __forceinline__ void gemm_chunk(float z[8][4], const float* __restrict__ A,
                                           const float* __restrict__ W, int m0, int j4) {
  #pragma unroll
  for (int k = 0; k < 16; ++k) {
    const float4 a0 = *(const float4*)(A + k * 260 + m0);
    const float4 a1 = *(const float4*)(A + k * 260 + m0 + 4);
    const float4 w  = *(const float4*)(W + k * 32 + j4);
    const float am[8] = { a0.x, a0.y, a0.z, a0.w, a1.x, a1.y, a1.z, a1.w };
    #pragma unroll
    for (int mi = 0; mi < 8; ++mi) {
      z[mi][0] += am[mi] * w.x;
      z[mi][1] += am[mi] * w.y;
      z[mi][2] += am[mi] * w.z;
      z[mi][3] += am[mi] * w.w;
    }
  }
}

// Persistent 2-layer LSTM + time-mean pool.
// grid 256 = 8 m-groups(256 seqs) x 32 j-groups(8 hidden cols); block 256 thr.
// Phase p: L1 -> h1[p] (p<50), L2 -> h2[p-1] (p>=1); one grid.sync per phase.
__global__ void __launch_bounds__(256, 1)
lstm_fused(const float* __restrict__ xin,
           const float* __restrict__ Wx1, const float* __restrict__ Wh1, const float* __restrict__ b1,
           const float* __restrict__ Wx2, const float* __restrict__ Wh2, const float* __restrict__ b2,
           float* __restrict__ h1a, float* __restrict__ h1b,
           float* __restrict__ h2a, float* __restrict__ h2b,
           float* __restrict__ xg)
{
  __shared__ float W1s[272 * 32];     // [k][j*4+g]: rows 0..15 = Wx1, 16..271 = Wh1
  __shared__ float W2s[512 * 32];     // rows 0..255 = Wx2 (input h1[t]), 256..511 = Wh2
  __shared__ float As[2 * 16 * 260];  // double-buffered A chunk, transposed
  __shared__ float bs[64];            // b1 slice | b2 slice

  const int tid  = threadIdx.x;
  const int blk  = blockIdx.x;
  const int mg   = blk >> 5, jg = blk & 31;
  const int mbase = mg << 8;                   // 256 seqs per m-group
  const int lane = tid & 63, wv = tid >> 6;
  const int j    = lane >> 3;                  // 0..7 (all 8 j per wave -> W broadcast)
  const int mq   = (wv << 3) + (lane & 7);     // 0..31
  const int m0   = mq << 3;                    // 8 seqs per thread
  const int jcol = (jg << 3) + j;
  const int j4   = j << 2;

  for (int idx = tid; idx < 272 * 32; idx += 256) {
    int k = idx >> 5, c = idx & 31;
    int col = ((c & 3) << 8) + (jg << 3) + (c >> 2);   // g*256 + jg*8 + jj
    W1s[idx] = (k < 16) ? Wx1[(k << 10) + col] : Wh1[((k - 16) << 10) + col];
  }
  for (int idx = tid; idx < 512 * 32; idx += 256) {
    int k = idx >> 5, c = idx & 31;
    int col = ((c & 3) << 8) + (jg << 3) + (c >> 2);
    W2s[idx] = (k < 256) ? Wx2[(k << 10) + col] : Wh2[((k - 256) << 10) + col];
  }
  if (tid < 64) {
    int c = tid & 31;
    int col = ((c & 3) << 8) + (jg << 3) + (c >> 2);
    bs[tid] = (tid < 32) ? b1[col] : b2[col];
  }

  float c1[8], c2[8], pool[8];
  #pragma unroll
  for (int i = 0; i < 8; ++i) { c1[i] = 0.0f; c2[i] = 0.0f; pool[i] = 0.0f; }

  float* const h1buf[2] = { h1a, h1b };
  float* const h2buf[2] = { h2a, h2b };

  cg::grid_group grid = cg::this_grid();
  __syncthreads();

  for (int p = 0; p <= TSTEPS; ++p) {
    // ---------------- Layer 1: h1[p] = cell(x[p], h1[p-1]) ----------------
    if (p < TSTEPS) {
      float z[8][4];
      #pragma unroll
      for (int mi = 0; mi < 8; ++mi) {
        z[mi][0] = bs[j4]; z[mi][1] = bs[j4 + 1]; z[mi][2] = bs[j4 + 2]; z[mi][3] = bs[j4 + 3];
      }
      const float* h1prev = h1buf[(p + 1) & 1];
      const int NC = p ? 17 : 1;     // chunk 0 = x_t (16 rows), 1..16 = h1prev
      float4 r[4];
      load_chunk(r, xin, mbase, 800, p << 4, tid);
      store_chunk(r, As, tid);
      if (NC > 1) load_chunk(r, h1prev, mbase, 256, 0, tid);
      __syncthreads();
      for (int cc = 0; cc < NC; ++cc) {
        if (cc + 1 < NC) {
          store_chunk(r, As + ((cc + 1) & 1) * 4160, tid);
          if (cc + 2 < NC) load_chunk(r, h1prev, mbase, 256, (cc + 1) << 4, tid);
        }
        gemm_chunk(z, As + (cc & 1) * 4160, W1s + (cc << 4) * 32, m0, j4);
        __syncthreads();
      }
      float* h1cur = h1buf[p & 1];
      #pragma unroll
      for (int mi = 0; mi < 8; ++mi) {
        float iv = sigm(z[mi][0]), fv = sigm(z[mi][1]);
        float gv = tanhf(z[mi][2]), ov = sigm(z[mi][3]);
        c1[mi] = fv * c1[mi] + iv * gv;
        h1cur[((mbase + m0 + mi) << 8) + jcol] = ov * tanhf(c1[mi]);
      }
    }
    // ---------------- Layer 2: h2[p-1] = cell(h1[p-1], h2[p-2]) -----------
    if (p >= 1) {
      float z[8][4];
      #pragma unroll
      for (int mi = 0; mi < 8; ++mi) {
        z[mi][0] = bs[32 + j4]; z[mi][1] = bs[32 + j4 + 1];
        z[mi][2] = bs[32 + j4 + 2]; z[mi][3] = bs[32 + j4 + 3];
      }
      const float* h1in = h1buf[(p + 1) & 1];   // h1[p-1]
      const float* h2in = h2buf[p & 1];         // h2[p-2] (unused when p==1)
      const int NC = (p >= 2) ? 32 : 16;        // 0..15 = h1in, 16..31 = h2in
      float4 r[4];
      load_chunk(r, h1in, mbase, 256, 0, tid);
      store_chunk(r, As, tid);
      if (NC > 1) load_chunk(r, h1in, mbase, 256, 16, tid);
      __syncthreads();
      for (int cc = 0; cc < NC; ++cc) {
        if (cc + 1 < NC) {
          store_chunk(r, As + ((cc + 1) & 1) * 4160, tid);
          if (cc + 2 < NC) {
            const int nn = cc + 2;
            load_chunk(r, (nn < 16) ? h1in : h2in, mbase, 256, (nn & 15) << 4, tid);
          }
        }
        gemm_chunk(z, As + (cc & 1) * 4160, W2s + (cc << 4) * 32, m0, j4);
        __syncthreads();
      }
      float* h2cur = h2buf[(p + 1) & 1];        // h2[p-1]
      #pragma unroll
      for (int mi = 0; mi < 8; ++mi) {
        float iv = sigm(z[mi][0]), fv = sigm(z[mi][1]);
        float gv = tanhf(z[mi][2]), ov = sigm(z[mi][3]);
        c2[mi] = fv * c2[mi] + iv * gv;
        float hv = ov * tanhf(c2[mi]);
        pool[mi] += hv;
        h2cur[((mbase + m0 + mi) << 8) + jcol] = hv;
      }
    }
    if (p < TSTEPS) { __threadfence(); grid.sync(); }
  }
  #pragma unroll
  for (int mi = 0; mi < 8; ++mi)
    xg[((mbase + m0 + mi) << 8) + jcol] = pool[mi] * (1.0f / 50.0f);
}

// ---- GAT ----------------------------------------------------------------
// hfeat = x @ gW; es/ed = per-head <hfeat, a_src/a_dst>. 8 rows per block.
__global__ void __launch_bounds__(256)
gat_feat(const float* __restrict__ xin, const float* __restrict__ gW,
         const float* __restrict__ a_src, const float* __restrict__ a_dst,
         float* __restrict__ hfeat, float* __restrict__ es, float* __restrict__ ed)
{
  __shared__ float Xs[8][260];
  const int tid = threadIdx.x;
  const int r0 = blockIdx.x << 3;
  #pragma unroll
  for (int i = 0; i < 8; ++i) Xs[i][tid] = xin[((r0 + i) << 8) + tid];
  __syncthreads();
  float acc[8];
  #pragma unroll
  for (int i = 0; i < 8; ++i) acc[i] = 0.0f;
  for (int k = 0; k < 256; k += 4) {
    const float w0 = gW[(k + 0) * 256 + tid];
    const float w1 = gW[(k + 1) * 256 + tid];
    const float w2 = gW[(k + 2) * 256 + tid];
    const float w3 = gW[(k + 3) * 256 + tid];
    #pragma unroll
    for (int i = 0; i < 8; ++i)
      acc[i] += Xs[i][k] * w0 + Xs[i][k + 1] * w1 + Xs[i][k + 2] * w2 + Xs[i][k + 3] * w3;
  }
  const int h = tid >> 6;        // wave w == head w (64 ch per head)
  const int lane = tid & 63;
  const float asv = a_src[(h << 6) + lane];
  const float adv = a_dst[(h << 6) + lane];
  #pragma unroll
  for (int i = 0; i < 8; ++i) {
    hfeat[((r0 + i) << 8) + tid] = acc[i];
    float pse = acc[i] * asv;
    float pde = acc[i] * adv;
    #pragma unroll
    for (int off = 32; off > 0; off >>= 1) {
      pse += __shfl_down(pse, off);
      pde += __shfl_down(pde, off);
    }
    if (lane == 0) {
      es[((r0 + i) << 2) + h] = pse;
      ed[((r0 + i) << 2) + h] = pde;
    }
  }
}

// Star graph: edges u->0 (u=0..31) then 0->u (u=0..31). Node 0 receives 33 edges
// (0->0 twice, identical logits); nodes v>=1 receive exactly one edge from node 0.
__global__ void __launch_bounds__(256)
gat_out(const float* __restrict__ hfeat, const float* __restrict__ es, const float* __restrict__ ed,
        const float* __restrict__ gb, float* __restrict__ yout)
{
  __shared__ float exs[32][4];
  __shared__ float invden[4];
  const int tid = threadIdx.x;
  const int rbase = blockIdx.x << 5;
  if (tid < 128) {
    const int u = tid >> 2, h = tid & 3;
    float l = es[((rbase + u) << 2) + h] + ed[(rbase << 2) + h];
    exs[u][h] = (l < 0.0f) ? 0.2f * l : l;   // leaky_relu 0.2
  }
  __syncthreads();
  if (tid < 4) {
    const int h = tid;
    float m = -1e30f;
    for (int u = 0; u < 32; ++u) m = fmaxf(m, exs[u][h]);
    float s = 0.0f;
    for (int u = 0; u < 32; ++u) { float e = expf(exs[u][h] - m); exs[u][h] = e; s += e; }
    s += exs[0][h];                          // duplicate 0->0 edge in denominator
    invden[h] = 1.0f / (s + 1e-9f);
  }
  __syncthreads();
  const int h = tid >> 6;
  const float h0 = hfeat[(rbase << 8) + tid];
  float s = exs[0][h] * h0;                  // duplicate 0->0 edge message
  for (int u = 0; u < 32; ++u)
    s += exs[u][h] * hfeat[((rbase + u) << 8) + tid];
  const float bias = gb[tid];
  const float inv1 = 1.0f / (1.0f + 1e-9f);  // alpha for single-edge segments
  yout[(rbase << 8) + tid] = gelu_t(s * invden[h] + bias);
  const float gv = gelu_t(h0 * inv1 + bias);
  for (int v = 1; v < 32; ++v)
    yout[((rbase + v) << 8) + tid] = gv;
}

// ---- launch -------------------------------------------------------------
extern "C" void kernel_launch(void* const* d_in, const int* in_sizes, int n_in,
                              void* d_out, int out_size, void* d_ws, size_t ws_size,
                              hipStream_t stream) {
  (void)in_sizes; (void)n_in; (void)out_size; (void)ws_size;
  const float* states = (const float*)d_in[0];
  const float* Wx1 = (const float*)d_in[1];
  const float* Wh1 = (const float*)d_in[2];
  const float* b1  = (const float*)d_in[3];
  const float* Wx2 = (const float*)d_in[4];
  const float* Wh2 = (const float*)d_in[5];
  const float* b2  = (const float*)d_in[6];
  const float* gW1 = (const float*)d_in[7];
  const float* gas1 = (const float*)d_in[8];
  const float* gad1 = (const float*)d_in[9];
  const float* gb1 = (const float*)d_in[10];
  const float* gW2 = (const float*)d_in[11];
  const float* gas2 = (const float*)d_in[12];
  const float* gad2 = (const float*)d_in[13];
  const float* gb2 = (const float*)d_in[14];

  float* ws = (float*)d_ws;
  const size_t NB = 2048 * 256;      // 2 MB per buffer
  float* h1a = ws;
  float* h1b = h1a + NB;
  float* h2a = h1b + NB;
  float* h2b = h2a + NB;
  float* xg  = h2b + NB;
  float* y1  = xg + NB;
  float* hfeat = y1 + NB;
  float* es = hfeat + NB;
  float* ed = es + 2048 * 4;
  float* dout = (float*)d_out;

  void* args[] = { (void*)&states, (void*)&Wx1, (void*)&Wh1, (void*)&b1,
                   (void*)&Wx2, (void*)&Wh2, (void*)&b2,
                   (void*)&h1a, (void*)&h1b, (void*)&h2a, (void*)&h2b, (void*)&xg };
  hipError_t err = hipLaunchCooperativeKernel((void*)lstm_fused, dim3(256), dim3(256),
                                              args, 0, stream);
  (void)err;

  gat_feat<<<dim3(256), dim3(256), 0, stream>>>(xg, gW1, gas1, gad1, hfeat, es, ed);
  gat_out<<<dim3(64), dim3(256), 0, stream>>>(hfeat, es, ed, gb1, y1);
  gat_feat<<<dim3(256), dim3(256), 0, stream>>>(y1, gW2, gas2, gad2, hfeat, es, ed);
  gat_out<<<dim3(64), dim3(256), 0, stream>>>(hfeat, es, ed, gb2, dout);
}

// Round 2
// 3197.175 us; speedup vs baseline: 1.7921x; 1.7921x over previous
//
#include <hip/hip_runtime.h>
#include <hip/hip_cooperative_groups.h>

namespace cg = cooperative_groups;

#define TSTEPS 50
// sizes: 2048 seqs, T=50, D=16, H=256 (gate cols 1024), GAT 256ch 4 heads

__device__ __forceinline__ float sigm(float x) { return 1.0f / (1.0f + expf(-x)); }
__device__ __forceinline__ float gelu_t(float x) {
  float x3 = x * x * x;
  return 0.5f * x * (1.0f + tanhf(0.7978845608028654f * (x + 0.044715f * x3)));
}

// per-m-group barrier: 32 blocks share one counter; monotonic target per phase.
__device__ __forceinline__ void mg_barrier(unsigned* bar, unsigned target) {
  __syncthreads();
  if (threadIdx.x == 0) {
    __threadfence();                       // release h-writes to device scope
    atomicAdd(bar, 1u);
    while (atomicAdd(bar, 0u) < target) __builtin_amdgcn_s_sleep(2);
    __threadfence();                       // acquire: invalidates CU L1
  }
  __syncthreads();
}

// x[seq][t*16+d] -> xT[t*16+d][seq]; also zeroes the barrier counters.
__global__ void __launch_bounds__(256)
transpose_x(const float* __restrict__ x, float* __restrict__ xT, unsigned* __restrict__ bar) {
  if (blockIdx.x == 0 && threadIdx.x < 256) bar[threadIdx.x] = 0u;
  __shared__ float Ts[64][65];
  const int st = blockIdx.x & 31;          // seq tile (2048/64)
  const int tt = blockIdx.x >> 5;          // td tile (13 tiles for 800)
  const int s0 = st << 6, t0 = tt << 6;
  const int r = threadIdx.x >> 6;          // 0..3
  const int c = threadIdx.x & 63;
  #pragma unroll
  for (int i = 0; i < 16; ++i) {
    int row = r + (i << 2);
    int td = t0 + c;
    if (td < 800) Ts[row][c] = x[(s0 + row) * 800 + td];
  }
  __syncthreads();
  #pragma unroll
  for (int i = 0; i < 16; ++i) {
    int row = r + (i << 2);
    int td = t0 + row;
    if (td < 800) xT[td * 2048 + s0 + c] = Ts[c][row];
  }
}

// Persistent 2-layer LSTM + time-mean pool.
// grid 256 = 8 mg (256 seqs) x 32 jg (8 hid cols); block 512 thr (8 waves).
// h buffers TRANSPOSED: h[jcol][2048 seqs] -> staging is a linear copy.
__global__ void __launch_bounds__(512, 1)
lstm_fused(const float* __restrict__ xT,
           const float* __restrict__ Wx1, const float* __restrict__ Wh1, const float* __restrict__ b1,
           const float* __restrict__ Wx2, const float* __restrict__ Wh2, const float* __restrict__ b2,
           float* __restrict__ h1a, float* __restrict__ h1b,
           float* __restrict__ h2a, float* __restrict__ h2b,
           float* __restrict__ xg, unsigned* __restrict__ bar)
{
  __shared__ float W1s[272 * 32];          // [k][j*4+g] rows: 0..15 Wx1, 16..271 Wh1
  __shared__ float W2s[512 * 32];          // rows: 0..255 Wx2, 256..511 Wh2
  __shared__ float As[2][16 * 256];        // double-buffered chunk, LINEAR [k][m]
  __shared__ float bs[64];

  const int tid = threadIdx.x;
  const int blk = blockIdx.x;
  const int mg = blk >> 5, jg = blk & 31;
  const int mbase = mg << 8;
  const int lane = tid & 63, wv = tid >> 6;
  const int j = lane >> 3;                 // 0..7
  const int mq = (wv << 3) + (lane & 7);   // 0..63
  const int m0 = mq << 2;                  // 4 seqs per thread
  const int jcol = (jg << 3) + j;
  const int j4 = j << 2;
  unsigned* mybar = bar + (mg << 5);

  for (int idx = tid; idx < 272 * 32; idx += 512) {
    int k = idx >> 5, c = idx & 31;
    int col = ((c & 3) << 8) + (jg << 3) + (c >> 2);   // g*256 + jcol
    W1s[idx] = (k < 16) ? Wx1[(k << 10) + col] : Wh1[((k - 16) << 10) + col];
  }
  for (int idx = tid; idx < 512 * 32; idx += 512) {
    int k = idx >> 5, c = idx & 31;
    int col = ((c & 3) << 8) + (jg << 3) + (c >> 2);
    W2s[idx] = (k < 256) ? Wx2[(k << 10) + col] : Wh2[((k - 256) << 10) + col];
  }
  if (tid < 64) {
    int c = tid & 31;
    int col = ((c & 3) << 8) + (jg << 3) + (c >> 2);
    bs[tid] = (tid < 32) ? b1[col] : b2[col];
  }

  float c1[4], c2[4], pool[4];
  #pragma unroll
  for (int i = 0; i < 4; ++i) { c1[i] = 0.0f; c2[i] = 0.0f; pool[i] = 0.0f; }

  float* const h1buf[2] = { h1a, h1b };
  float* const h2buf[2] = { h2a, h2b };

  const int krow = tid >> 6;               // 0..7
  const int coff = (tid & 63) << 2;

  // stage 16 rows x 256 cols: rowbase already includes mbase
  auto ldrows = [&](const float* rowbase, float4& r0, float4& r1) {
    r0 = *(const float4*)(rowbase + krow * 2048 + coff);
    r1 = *(const float4*)(rowbase + (krow + 8) * 2048 + coff);
  };
  auto strows = [&](float* A, const float4& r0, const float4& r1) {
    ((float4*)A)[tid] = r0;                // conflict-free b128 writes
    ((float4*)A)[tid + 512] = r1;
  };
  auto gemm16 = [&](float z[4][4], const float* A, const float* W) {
    #pragma unroll
    for (int k = 0; k < 16; ++k) {
      const float4 a = *(const float4*)(A + (k << 8) + m0);
      const float4 w = *(const float4*)(W + (k << 5) + j4);
      z[0][0] += a.x * w.x; z[0][1] += a.x * w.y; z[0][2] += a.x * w.z; z[0][3] += a.x * w.w;
      z[1][0] += a.y * w.x; z[1][1] += a.y * w.y; z[1][2] += a.y * w.z; z[1][3] += a.y * w.w;
      z[2][0] += a.z * w.x; z[2][1] += a.z * w.y; z[2][2] += a.z * w.z; z[2][3] += a.z * w.w;
      z[3][0] += a.w * w.x; z[3][1] += a.w * w.y; z[3][2] += a.w * w.z; z[3][3] += a.w * w.w;
    }
  };

  __syncthreads();

  for (int p = 0; p <= TSTEPS; ++p) {
    // ---- Layer 1: h1[p] = cell(x[p], h1[p-1]) ----
    if (p < TSTEPS) {
      float z[4][4];
      #pragma unroll
      for (int mi = 0; mi < 4; ++mi) {
        z[mi][0] = bs[j4]; z[mi][1] = bs[j4 + 1]; z[mi][2] = bs[j4 + 2]; z[mi][3] = bs[j4 + 3];
      }
      const float* h1prev = h1buf[(p + 1) & 1];
      const int NC = p ? 17 : 1;           // chunk 0 = x_t, 1..16 = h1prev
      float4 r0, r1;
      ldrows(xT + p * 16 * 2048 + mbase, r0, r1);
      strows(As[0], r0, r1);
      if (NC > 1) ldrows(h1prev + mbase, r0, r1);
      __syncthreads();
      for (int cc = 0; cc < NC; ++cc) {
        if (cc + 1 < NC) {
          strows(As[(cc + 1) & 1], r0, r1);
          if (cc + 2 < NC) ldrows(h1prev + ((cc + 1) << 4) * 2048 + mbase, r0, r1);
        }
        gemm16(z, As[cc & 1], W1s + (cc << 9));
        __syncthreads();
      }
      float* h1cur = h1buf[p & 1];
      float4 hv;
      #pragma unroll
      for (int mi = 0; mi < 4; ++mi) {
        float iv = sigm(z[mi][0]), fv = sigm(z[mi][1]);
        float gv = tanhf(z[mi][2]), ov = sigm(z[mi][3]);
        c1[mi] = fv * c1[mi] + iv * gv;
        ((float*)&hv)[mi] = ov * tanhf(c1[mi]);
      }
      *(float4*)(h1cur + jcol * 2048 + mbase + m0) = hv;
    }
    // ---- Layer 2: h2[p-1] = cell(h1[p-1], h2[p-2]) ----
    if (p >= 1) {
      float z[4][4];
      #pragma unroll
      for (int mi = 0; mi < 4; ++mi) {
        z[mi][0] = bs[32 + j4]; z[mi][1] = bs[32 + j4 + 1];
        z[mi][2] = bs[32 + j4 + 2]; z[mi][3] = bs[32 + j4 + 3];
      }
      const float* h1in = h1buf[(p + 1) & 1];   // h1[p-1]
      const float* h2in = h2buf[p & 1];         // h2[p-2]
      const int NC = (p >= 2) ? 32 : 16;        // 0..15 h1in, 16..31 h2in
      float4 r0, r1;
      ldrows(h1in + mbase, r0, r1);
      strows(As[0], r0, r1);
      ldrows(h1in + 16 * 2048 + mbase, r0, r1);
      __syncthreads();
      for (int cc = 0; cc < NC; ++cc) {
        if (cc + 1 < NC) {
          strows(As[(cc + 1) & 1], r0, r1);
          if (cc + 2 < NC) {
            const int nn = cc + 2;
            const float* b = (nn < 16) ? (h1in + (nn << 4) * 2048)
                                       : (h2in + ((nn - 16) << 4) * 2048);
            ldrows(b + mbase, r0, r1);
          }
        }
        gemm16(z, As[cc & 1], W2s + (cc << 9));
        __syncthreads();
      }
      float* h2cur = h2buf[(p + 1) & 1];
      float4 hv;
      #pragma unroll
      for (int mi = 0; mi < 4; ++mi) {
        float iv = sigm(z[mi][0]), fv = sigm(z[mi][1]);
        float gv = tanhf(z[mi][2]), ov = sigm(z[mi][3]);
        c2[mi] = fv * c2[mi] + iv * gv;
        float h = ov * tanhf(c2[mi]);
        pool[mi] += h;
        ((float*)&hv)[mi] = h;
      }
      *(float4*)(h2cur + jcol * 2048 + mbase + m0) = hv;
    }
    if (p < TSTEPS) mg_barrier(mybar, (unsigned)(p + 1) * 32u);
  }
  #pragma unroll
  for (int mi = 0; mi < 4; ++mi)
    xg[((mbase + m0 + mi) << 8) + jcol] = pool[mi] * (1.0f / 50.0f);   // row-major [seq][256]
}

// ---- GAT ----------------------------------------------------------------
__global__ void __launch_bounds__(256)
gat_feat(const float* __restrict__ xin, const float* __restrict__ gW,
         const float* __restrict__ a_src, const float* __restrict__ a_dst,
         float* __restrict__ hfeat, float* __restrict__ es, float* __restrict__ ed)
{
  __shared__ float Xs[8][260];
  const int tid = threadIdx.x;
  const int r0 = blockIdx.x << 3;
  #pragma unroll
  for (int i = 0; i < 8; ++i) Xs[i][tid] = xin[((r0 + i) << 8) + tid];
  __syncthreads();
  float acc[8];
  #pragma unroll
  for (int i = 0; i < 8; ++i) acc[i] = 0.0f;
  for (int k = 0; k < 256; k += 4) {
    const float w0 = gW[(k + 0) * 256 + tid];
    const float w1 = gW[(k + 1) * 256 + tid];
    const float w2 = gW[(k + 2) * 256 + tid];
    const float w3 = gW[(k + 3) * 256 + tid];
    #pragma unroll
    for (int i = 0; i < 8; ++i)
      acc[i] += Xs[i][k] * w0 + Xs[i][k + 1] * w1 + Xs[i][k + 2] * w2 + Xs[i][k + 3] * w3;
  }
  const int h = tid >> 6;
  const int lane = tid & 63;
  const float asv = a_src[(h << 6) + lane];
  const float adv = a_dst[(h << 6) + lane];
  #pragma unroll
  for (int i = 0; i < 8; ++i) {
    hfeat[((r0 + i) << 8) + tid] = acc[i];
    float pse = acc[i] * asv;
    float pde = acc[i] * adv;
    #pragma unroll
    for (int off = 32; off > 0; off >>= 1) {
      pse += __shfl_down(pse, off);
      pde += __shfl_down(pde, off);
    }
    if (lane == 0) {
      es[((r0 + i) << 2) + h] = pse;
      ed[((r0 + i) << 2) + h] = pde;
    }
  }
}

__global__ void __launch_bounds__(256)
gat_out(const float* __restrict__ hfeat, const float* __restrict__ es, const float* __restrict__ ed,
        const float* __restrict__ gb, float* __restrict__ yout)
{
  __shared__ float exs[32][4];
  __shared__ float invden[4];
  const int tid = threadIdx.x;
  const int rbase = blockIdx.x << 5;
  if (tid < 128) {
    const int u = tid >> 2, h = tid & 3;
    float l = es[((rbase + u) << 2) + h] + ed[(rbase << 2) + h];
    exs[u][h] = (l < 0.0f) ? 0.2f * l : l;
  }
  __syncthreads();
  if (tid < 4) {
    const int h = tid;
    float m = -1e30f;
    for (int u = 0; u < 32; ++u) m = fmaxf(m, exs[u][h]);
    float s = 0.0f;
    for (int u = 0; u < 32; ++u) { float e = expf(exs[u][h] - m); exs[u][h] = e; s += e; }
    s += exs[0][h];                        // duplicate 0->0 edge
    invden[h] = 1.0f / (s + 1e-9f);
  }
  __syncthreads();
  const int h = tid >> 6;
  const float h0 = hfeat[(rbase << 8) + tid];
  float s = exs[0][h] * h0;
  for (int u = 0; u < 32; ++u)
    s += exs[u][h] * hfeat[((rbase + u) << 8) + tid];
  const float bias = gb[tid];
  const float inv1 = 1.0f / (1.0f + 1e-9f);
  yout[(rbase << 8) + tid] = gelu_t(s * invden[h] + bias);
  const float gv = gelu_t(h0 * inv1 + bias);
  for (int v = 1; v < 32; ++v)
    yout[((rbase + v) << 8) + tid] = gv;
}

// ---- launch -------------------------------------------------------------
extern "C" void kernel_launch(void* const* d_in, const int* in_sizes, int n_in,
                              void* d_out, int out_size, void* d_ws, size_t ws_size,
                              hipStream_t stream) {
  (void)in_sizes; (void)n_in; (void)out_size; (void)ws_size;
  const float* states = (const float*)d_in[0];
  const float* Wx1 = (const float*)d_in[1];
  const float* Wh1 = (const float*)d_in[2];
  const float* b1  = (const float*)d_in[3];
  const float* Wx2 = (const float*)d_in[4];
  const float* Wh2 = (const float*)d_in[5];
  const float* b2  = (const float*)d_in[6];
  const float* gW1 = (const float*)d_in[7];
  const float* gas1 = (const float*)d_in[8];
  const float* gad1 = (const float*)d_in[9];
  const float* gb1 = (const float*)d_in[10];
  const float* gW2 = (const float*)d_in[11];
  const float* gas2 = (const float*)d_in[12];
  const float* gad2 = (const float*)d_in[13];
  const float* gb2 = (const float*)d_in[14];

  float* ws = (float*)d_ws;
  const size_t NB = 2048 * 256;            // 2 MB per buffer
  float* h1a = ws;
  float* h1b = h1a + NB;
  float* h2a = h1b + NB;
  float* h2b = h2a + NB;
  float* xg  = h2b + NB;
  float* xT  = xg + NB;                    // 50*16*2048 floats
  unsigned* bar = (unsigned*)(xT + 50 * 16 * 2048);
  // post-LSTM aliases (h buffers are dead once lstm_fused completes)
  float* y1    = h1a;
  float* hfeat = h1b;
  float* es    = h2a;
  float* ed    = h2a + 2048 * 4;
  float* dout  = (float*)d_out;

  transpose_x<<<dim3(32 * 13), dim3(256), 0, stream>>>(states, xT, bar);

  void* args[] = { (void*)&xT, (void*)&Wx1, (void*)&Wh1, (void*)&b1,
                   (void*)&Wx2, (void*)&Wh2, (void*)&b2,
                   (void*)&h1a, (void*)&h1b, (void*)&h2a, (void*)&h2b,
                   (void*)&xg, (void*)&bar };
  hipError_t err = hipLaunchCooperativeKernel((void*)lstm_fused, dim3(256), dim3(512),
                                              args, 0, stream);
  (void)err;

  gat_feat<<<dim3(256), dim3(256), 0, stream>>>(xg, gW1, gas1, gad1, hfeat, es, ed);
  gat_out<<<dim3(64), dim3(256), 0, stream>>>(hfeat, es, ed, gb1, y1);
  gat_feat<<<dim3(256), dim3(256), 0, stream>>>(y1, gW2, gas2, gad2, hfeat, es, ed);
  gat_out<<<dim3(64), dim3(256), 0, stream>>>(hfeat, es, ed, gb2, dout);
}